// Round 2
// baseline (1187.775 us; speedup 1.0000x reference)
//
#include <hip/hip_runtime.h>
#include <hip/hip_bf16.h>

typedef __bf16 bf16_t;
typedef __bf16 bf16x8 __attribute__((ext_vector_type(8)));
typedef float f32x4 __attribute__((ext_vector_type(4)));

constexpr int Hh = 56;
constexpr int Ww = 56;
constexpr int Cc = 512;
constexpr int NHd = 16;
constexpr int HD = 32;
constexpr int SSh = 3;
constexpr int Nn = 49;          // tokens per window
constexpr long Mtot = 100352;   // 32*64*49 windowed tokens
#define SCALE 0.17677669529663687f

// token (windowed order) -> pixel index in x / out. Identical map for gather and scatter.
__device__ __forceinline__ int token_to_pixel(int m) {
  int bw = m / Nn;
  int n  = m - bw * Nn;
  int b  = bw >> 6;
  int w6 = bw & 63;
  int wh = w6 >> 3, ww = w6 & 7;
  int r = n / 7, c = n - r * 7;
  int hh = wh * 7 + r + SSh; if (hh >= Hh) hh -= Hh;
  int wp = ww * 7 + c + SSh; if (wp >= Ww) wp -= Ww;
  return (b * Hh + hh) * Ww + wp;
}

// C[m][n] = sum_k A[m][k]*W[n][k] (+bias).
// MODE 0: A = x (f32, rows gathered via shifted-window map), W = qkv_w (f32);
//         scatter bf16 q/k/v into (bw,h,n,d) layout.
// MODE 1: A = attn_out (bf16, contiguous rows), W = proj_w (f32);
//         scatter f32 output to rolled pixel layout.
template <int MODE>
__global__ __launch_bounds__(256, 2)
void gemm_k(const void* __restrict__ Asrc_, const float* __restrict__ Wt,
            const float* __restrict__ bias,
            bf16_t* __restrict__ oq, bf16_t* __restrict__ okk, bf16_t* __restrict__ ov,
            float* __restrict__ of) {
  __shared__ __align__(16) bf16_t lA[128 * 32];
  __shared__ __align__(16) bf16_t lB[128 * 32];
  const int t = threadIdx.x;
  const int mtile = blockIdx.x, ntile = blockIdx.y;
  const int lane = t & 63;
  const int wave = t >> 6;
  const int wr = wave >> 1, wc = wave & 1;
  const int quad = lane >> 4, l15 = lane & 15;

  // staging: thread t covers row0 (+64), cols part*8..part*8+8 of the k-slab
  const int row0 = t >> 2, part = t & 3;
  const float* aPtrF[2];
  const bf16_t* aPtrB[2];
  const float* bPtrF[2];
#pragma unroll
  for (int u = 0; u < 2; ++u) {
    int rA = row0 + u * 64;
    int m = mtile * 128 + rA;
    if (MODE == 0) {
      aPtrF[u] = (const float*)Asrc_ + (long)token_to_pixel(m) * Cc + part * 8;
    } else {
      aPtrB[u] = (const bf16_t*)Asrc_ + (long)m * Cc + part * 8;
    }
    int nIdx = ntile * 128 + rA;
    bPtrF[u] = Wt + (long)nIdx * Cc + part * 8;
  }

  f32x4 acc[4][4] = {};

  for (int k0 = 0; k0 < Cc; k0 += 32) {
    // global -> registers (f32), convert -> bf16
    bf16x8 aReg[2], bReg[2];
#pragma unroll
    for (int u = 0; u < 2; ++u) {
      if (MODE == 0) {
        f32x4 a0 = *(const f32x4*)(aPtrF[u] + k0);
        f32x4 a1 = *(const f32x4*)(aPtrF[u] + k0 + 4);
#pragma unroll
        for (int e = 0; e < 4; ++e) { aReg[u][e] = (bf16_t)a0[e]; aReg[u][e + 4] = (bf16_t)a1[e]; }
      } else {
        aReg[u] = *(const bf16x8*)(aPtrB[u] + k0);
      }
      f32x4 b0 = *(const f32x4*)(bPtrF[u] + k0);
      f32x4 b1 = *(const f32x4*)(bPtrF[u] + k0 + 4);
#pragma unroll
      for (int e = 0; e < 4; ++e) { bReg[u][e] = (bf16_t)b0[e]; bReg[u][e + 4] = (bf16_t)b1[e]; }
    }
    __syncthreads();   // previous iteration's fragment reads complete
    *(bf16x8*)(lA + t * 8)        = aReg[0];
    *(bf16x8*)(lA + t * 8 + 2048) = aReg[1];
    *(bf16x8*)(lB + t * 8)        = bReg[0];
    *(bf16x8*)(lB + t * 8 + 2048) = bReg[1];
    __syncthreads();   // stores visible

    bf16x8 af[4], bfr[4];
#pragma unroll
    for (int i = 0; i < 4; ++i)
      af[i] = *(const bf16x8*)(lA + (wr * 64 + i * 16 + l15) * 32 + quad * 8);
#pragma unroll
    for (int j = 0; j < 4; ++j)
      bfr[j] = *(const bf16x8*)(lB + (wc * 64 + j * 16 + l15) * 32 + quad * 8);
#pragma unroll
    for (int i = 0; i < 4; ++i)
#pragma unroll
      for (int j = 0; j < 4; ++j)
        acc[i][j] = __builtin_amdgcn_mfma_f32_16x16x32_bf16(af[i], bfr[j], acc[i][j], 0, 0, 0);
  }

#pragma unroll
  for (int i = 0; i < 4; ++i) {
#pragma unroll
    for (int rg = 0; rg < 4; ++rg) {
      int m = mtile * 128 + wr * 64 + i * 16 + quad * 4 + rg;
      if (MODE == 0) {
        int bw = m / Nn, n = m - bw * Nn;
#pragma unroll
        for (int j = 0; j < 4; ++j) {
          int jg = ntile * 128 + wc * 64 + j * 16 + l15;
          float v = acc[i][j][rg] + bias[jg];
          int which = jg >> 9;
          int h = (jg >> 5) & 15;
          int d = jg & 31;
          long idx = (((long)bw * NHd + h) * Nn + n) * HD + d;
          bf16_t* dst = (which == 0) ? oq : ((which == 1) ? okk : ov);
          dst[idx] = (bf16_t)v;
        }
      } else {
        long pb = (long)token_to_pixel(m) * Cc;
#pragma unroll
        for (int j = 0; j < 4; ++j) {
          int jg = ntile * 128 + wc * 64 + j * 16 + l15;
          of[pb + jg] = acc[i][j][rg] + bias[jg];
        }
      }
    }
  }
}

// one block per window; wave w handles heads 4w..4w+3; lane l<49 owns query row l.
// writes attn_out (token-major, C=h*32+d) over the q region (block-local, after all reads).
__global__ __launch_bounds__(256, 2)
void attn_k(bf16_t* qr, const bf16_t* __restrict__ kr, const bf16_t* __restrict__ vr,
            const float* __restrict__ table) {
  __shared__ __align__(16) bf16_t kbuf[4][Nn * HD];
  __shared__ __align__(16) bf16_t vbuf[4][Nn * HD];
  __shared__ __align__(16) bf16_t obuf[Nn * Cc];
  const int t = threadIdx.x, wave = t >> 6, lane = t & 63;
  const int bw = blockIdx.x;
  const int w6 = bw & 63, wh = w6 >> 3, ww = w6 & 7;

  const int r1 = lane / 7, c1 = lane - r1 * 7;  // valid when lane<49
  const int reg1 = ((wh == 7) ? ((r1 < 4) ? 1 : 2) : 0) * 3 +
                   ((ww == 7) ? ((c1 < 4) ? 1 : 2) : 0);

#pragma unroll 1
  for (int hi = 0; hi < 4; ++hi) {
    const int h = wave * 4 + hi;
    const long base = (((long)bw * NHd + h) * Nn) * HD;
    for (int c = lane; c < 196; c += 64) {
      *(f32x4*)((char*)kbuf[wave] + c * 16) = *(const f32x4*)((const char*)(kr + base) + c * 16);
      *(f32x4*)((char*)vbuf[wave] + c * 16) = *(const f32x4*)((const char*)(vr + base) + c * 16);
    }
    __syncthreads();
    if (lane < Nn) {
      float qf[32];
      const bf16x8* q8 = (const bf16x8*)(qr + base + (long)lane * HD);
#pragma unroll
      for (int u = 0; u < 4; ++u) {
        bf16x8 qq = q8[u];
#pragma unroll
        for (int e = 0; e < 8; ++e) qf[u * 8 + e] = (float)qq[e];
      }
      float o[32];
#pragma unroll
      for (int d = 0; d < 32; ++d) o[d] = 0.f;
      float ssum = 0.f;
#pragma unroll 1
      for (int m = 0; m < Nn; ++m) {
        const bf16x8* k8 = (const bf16x8*)(kbuf[wave] + m * HD);
        float a = 0.f;
#pragma unroll
        for (int u = 0; u < 4; ++u) {
          bf16x8 kk = k8[u];
#pragma unroll
          for (int e = 0; e < 8; ++e) a += qf[u * 8 + e] * (float)kk[e];
        }
        a *= SCALE;
        int r2 = m / 7, c2 = m - r2 * 7;
        int idx = (r1 - r2 + 6) * 13 + (c1 - c2 + 6);
        a += table[idx * NHd + h];
        int reg2 = ((wh == 7) ? ((r2 < 4) ? 1 : 2) : 0) * 3 +
                   ((ww == 7) ? ((c2 < 4) ? 1 : 2) : 0);
        a = (reg2 == reg1) ? a : (a - 100.f);
        // logits are O(1); exp without max-subtraction is safe in fp32
        float e = __expf(a);
        ssum += e;
        const bf16x8* v8 = (const bf16x8*)(vbuf[wave] + m * HD);
#pragma unroll
        for (int u = 0; u < 4; ++u) {
          bf16x8 vv = v8[u];
#pragma unroll
          for (int ee = 0; ee < 8; ++ee) o[u * 8 + ee] += e * (float)vv[ee];
        }
      }
      float inv = 1.f / ssum;
      bf16_t* ob = obuf + lane * Cc + h * HD;
#pragma unroll
      for (int d = 0; d < 32; ++d) ob[d] = (bf16_t)(o[d] * inv);
    }
    __syncthreads();
  }
  // contiguous 50 KB store of this window's attn_out into the q region
  bf16_t* dst = qr + (long)bw * (Nn * Cc);
  for (int c = t; c < (Nn * Cc * 2) / 16; c += 256)
    *(f32x4*)((char*)dst + c * 16) = *(const f32x4*)((const char*)obuf + c * 16);
}

extern "C" void kernel_launch(void* const* d_in, const int* in_sizes, int n_in,
                              void* d_out, int out_size, void* d_ws, size_t ws_size,
                              hipStream_t stream) {
  const float* x      = (const float*)d_in[0];
  const float* qkv_w  = (const float*)d_in[1];
  const float* qkv_b  = (const float*)d_in[2];
  const float* proj_w = (const float*)d_in[3];
  const float* proj_b = (const float*)d_in[4];
  const float* table  = (const float*)d_in[5];
  float* out = (float*)d_out;

  bf16_t* qr = (bf16_t*)d_ws;                 // q, later overwritten with attn_out
  bf16_t* kr = qr + Mtot * Cc;
  bf16_t* vr = kr + Mtot * Cc;

  dim3 g1(784, 12);
  gemm_k<0><<<g1, 256, 0, stream>>>(x, qkv_w, qkv_b, qr, kr, vr, nullptr);
  attn_k<<<2048, 256, 0, stream>>>(qr, kr, vr, table);
  dim3 g3(784, 4);
  gemm_k<1><<<g3, 256, 0, stream>>>(qr, proj_w, proj_b, nullptr, nullptr, nullptr, out);
}